// Round 1
// baseline (744.798 us; speedup 1.0000x reference)
//
#include <hip/hip_runtime.h>

// Problem constants (reference: B=256, T=4000, H=4, 29 classes)
#define HH 4
#define BB 256
#define TT 4000
#define NC 29

// Broadcast the value held by lane (quadbase+k) to all 4 lanes of each quad.
// DPP quad_perm: ctrl = k | k<<2 | k<<4 | k<<6 = k*0x55. ~VALU latency.
__device__ __forceinline__ float bcast_quad(float v, const int k) {
    int i = __float_as_int(v);
    int r;
    switch (k) {
        case 0:  r = __builtin_amdgcn_mov_dpp(i, 0x00, 0xF, 0xF, true); break;
        case 1:  r = __builtin_amdgcn_mov_dpp(i, 0x55, 0xF, 0xF, true); break;
        case 2:  r = __builtin_amdgcn_mov_dpp(i, 0xAA, 0xF, 0xF, true); break;
        default: r = __builtin_amdgcn_mov_dpp(i, 0xFF, 0xF, 0xF, true); break;
    }
    return __int_as_float(r);
}

// sigmoid(x) = 1/(1+exp(-x)) : v_mul(+neg fold) + v_exp + v_add + v_rcp
__device__ __forceinline__ float sigf(float x) {
    float e = __expf(-x);
    return __builtin_amdgcn_rcpf(1.0f + e);
}

// tanh(x) = 1 - 2/(exp(2x)+1) : mul + exp + add + rcp + fma
__device__ __forceinline__ float tanh_fast(float x) {
    float e = __expf(2.0f * x);
    float r = __builtin_amdgcn_rcpf(e + 1.0f);
    return fmaf(-2.0f, r, 1.0f);
}

// Balanced-tree 4-dot + base: depth = fma,fma / fma -> add (~3 deps)
__device__ __forceinline__ float gate_dot(float base, float4 W,
                                          float h0, float h1, float h2, float h3) {
    float a = fmaf(W.y, h1, fmaf(W.x, h0, base));
    float b = fmaf(W.w, h3, W.z * h2);
    return a + b;
}

// One wave (64 lanes) per block; 4 lanes per sequence (lane%4 = hidden unit).
// 16 blocks x 64 = 1024 threads = 256 sequences.
__global__ __launch_bounds__(64, 1) void lstm_kernel(
    const float* __restrict__ x,      // (B, T)
    const float* __restrict__ W_ih,   // (16, 1)
    const float* __restrict__ W_hh,   // (16, 4)
    const float* __restrict__ b_ih,   // (16,)
    const float* __restrict__ b_hh,   // (16,)
    float* __restrict__ hs)           // (B, T, 4) workspace
{
    const int tid = blockIdx.x * 64 + threadIdx.x;
    const int b   = tid >> 2;
    const int u   = tid & 3;

    // Gate rows for this lane: i=u, f=4+u, g=8+u, o=12+u (jnp.split order)
    const int ri = u, rf = 4 + u, rg = 8 + u, ro = 12 + u;

    const float wi_i = W_ih[ri], wi_f = W_ih[rf], wi_g = W_ih[rg], wi_o = W_ih[ro];
    const float bi = b_ih[ri] + b_hh[ri];
    const float bf = b_ih[rf] + b_hh[rf];
    const float bg = b_ih[rg] + b_hh[rg];
    const float bo = b_ih[ro] + b_hh[ro];

    const float4* Wrows = reinterpret_cast<const float4*>(W_hh); // 16B rows, aligned
    const float4 Wi = Wrows[ri];
    const float4 Wf = Wrows[rf];
    const float4 Wg = Wrows[rg];
    const float4 Wo = Wrows[ro];

    const float* xp = x + (size_t)b * TT;
    float*       hp = hs + (size_t)b * TT * 4 + u;

    float c = 0.0f;
    float h0 = 0.0f, h1 = 0.0f, h2 = 0.0f, h3 = 0.0f;

    // Software-pipelined x prefetch: hold 4 steps of x, load next chunk early.
    float4 xc = *reinterpret_cast<const float4*>(xp);

    for (int t0 = 0; t0 < TT; t0 += 4) {
        // Prefetch next 4 x values (clamped on last iter; redundant load, no branch)
        const int tn = (t0 + 4 < TT) ? (t0 + 4) : (TT - 4);
        float4 xn = *reinterpret_cast<const float4*>(xp + tn);

        #pragma unroll
        for (int j = 0; j < 4; ++j) {
            const float xt = (j == 0) ? xc.x : (j == 1) ? xc.y : (j == 2) ? xc.z : xc.w;

            float ai = fmaf(xt, wi_i, bi);
            float af = fmaf(xt, wi_f, bf);
            float ag = fmaf(xt, wi_g, bg);
            float ao = fmaf(xt, wi_o, bo);

            ai = gate_dot(ai, Wi, h0, h1, h2, h3);
            af = gate_dot(af, Wf, h0, h1, h2, h3);
            ag = gate_dot(ag, Wg, h0, h1, h2, h3);
            ao = gate_dot(ao, Wo, h0, h1, h2, h3);

            const float ig = sigf(ai);
            const float fg = sigf(af);
            const float gg = tanh_fast(ag);
            const float og = sigf(ao);

            c = fmaf(fg, c, ig * gg);
            const float tc = tanh_fast(c);
            const float h  = og * tc;

            // Broadcast the quad's 4 h values for the next step (DPP, cheap)
            h0 = bcast_quad(h, 0);
            h1 = bcast_quad(h, 1);
            h2 = bcast_quad(h, 2);
            h3 = bcast_quad(h, 3);

            hp[(t0 + j) * 4] = h;
        }
        xc = xn;
    }
}

// FC epilogue: out[b][t][c] = dot(hs[b][t][:], W_fc[c][:]) + b_fc[c]
// 32-lane groups; lane c in [0,29) computes class c for one (b,t) per iter.
// Reads: one float4 per group (broadcast). Writes: 29 contiguous floats/group.
__global__ __launch_bounds__(256) void fc_kernel(
    const float* __restrict__ hs,     // (B*T, 4)
    const float* __restrict__ W_fc,   // (29, 4)
    const float* __restrict__ b_fc,   // (29,)
    float* __restrict__ out)          // (B*T, 29)
{
    const int lane    = threadIdx.x & 31;
    const int group   = (blockIdx.x * blockDim.x + threadIdx.x) >> 5;
    const int ngroups = (gridDim.x * blockDim.x) >> 5;

    const int cc = (lane < NC) ? lane : 0;
    const float4 w  = reinterpret_cast<const float4*>(W_fc)[cc];
    const float bias = b_fc[cc];

    const int NBT = BB * TT;
    for (int bt = group; bt < NBT; bt += ngroups) {
        const float4 h = reinterpret_cast<const float4*>(hs)[bt];
        float v = fmaf(w.x, h.x, fmaf(w.y, h.y, fmaf(w.z, h.z, fmaf(w.w, h.w, bias))));
        if (lane < NC) out[(size_t)bt * NC + lane] = v;
    }
}

extern "C" void kernel_launch(void* const* d_in, const int* in_sizes, int n_in,
                              void* d_out, int out_size, void* d_ws, size_t ws_size,
                              hipStream_t stream) {
    const float* x    = (const float*)d_in[0];
    const float* W_ih = (const float*)d_in[1];
    const float* W_hh = (const float*)d_in[2];
    const float* b_ih = (const float*)d_in[3];
    const float* b_hh = (const float*)d_in[4];
    const float* W_fc = (const float*)d_in[5];
    const float* b_fc = (const float*)d_in[6];
    float* out = (float*)d_out;
    float* hs  = (float*)d_ws;   // needs B*T*4*4 = 16.384 MB

    // Recurrence: 256 sequences x 4 lanes = 1024 threads = 16 single-wave blocks
    lstm_kernel<<<16, 64, 0, stream>>>(x, W_ih, W_hh, b_ih, b_hh, hs);

    // FC: memory-bound epilogue, saturate the chip
    fc_kernel<<<4096, 256, 0, stream>>>(hs, W_fc, b_fc, out);
}

// Round 3
// 693.059 us; speedup vs baseline: 1.0747x; 1.0747x over previous
//
#include <hip/hip_runtime.h>

// Problem constants (reference: B=256, T=4000, H=4, 29 classes)
#define HH 4
#define BB 256
#define TT 4000
#define NC 29

// ---- DPP helpers (compile-time ctrl) ----
template<int CTRL>
__device__ __forceinline__ int dppi(int v) {
    return __builtin_amdgcn_mov_dpp(v, CTRL, 0xF, 0xF, true);
}
template<int CTRL>
__device__ __forceinline__ float dppf(float v) {
    return __int_as_float(dppi<CTRL>(__float_as_int(v)));
}
#define QB0   0x00   // quad_perm broadcast lane0 of quad
#define QB1   0x55
#define QB2   0xAA
#define QB3   0xFF
#define ROR4  0x124  // row_ror:4  (within 16-lane row)
#define ROR8  0x128  // row_ror:8
#define ROR12 0x12C  // row_ror:12

__device__ __forceinline__ float ex2(float x) { return __builtin_amdgcn_exp2f(x); }
__device__ __forceinline__ float rcpf_(float x) { return __builtin_amdgcn_rcpf(x); }

// 16 lanes per sequence: lane = q*4 + t, q = unit (0..3), t = gate type
// (0=i,1=f,2=g,3=o). Lane owns W_hh row = t*4+q (jnp.split order: i rows 0-3,
// f 4-7, g 8-11, o 12-15).
//
// Weights pre-scaled by s = log2e (i,f,o) or 2*log2e (g) so the gate dot
// directly yields the exp2 argument:
//   sigmoid(a) = 1 - rcp(1 + exp2(a*log2e))        -> act = fma(-1, rr, 1)
//   tanh(a)    = 1 - 2*rcp(1 + exp2(a*2log2e))
// g-gate act additionally pre-scaled by K2=2log2e:  act = fma(-2K2, rr, K2)
// so the c state is kept in K2-scaled form and tanh(c) needs no input mul:
//   tanh(c_true) = 1 - 2*rcp(1 + exp2(c_state)).
__global__ __launch_bounds__(64, 1) void lstm_kernel(
    const float* __restrict__ x,      // (B, T)
    const float* __restrict__ W_ih,   // (16, 1)
    const float* __restrict__ W_hh,   // (16, 4)
    const float* __restrict__ b_ih,   // (16,)
    const float* __restrict__ b_hh,   // (16,)
    float* __restrict__ hs)           // (B, T, 4) workspace
{
    const int lane = threadIdx.x;        // 0..63, one wave per block
    const int sl   = lane >> 4;          // sequence slot within wave (0..3)
    const int r    = lane & 15;
    const int q    = r >> 2;             // hidden unit
    const int t    = r & 3;              // gate type
    const int b    = blockIdx.x * 4 + sl;
    const int row  = t * 4 + q;

    const float L2E = 1.4426950408889634f;
    const float K2  = 2.0f * L2E;
    const float s   = (t == 2) ? K2 : L2E;
    const float ka  = (t == 2) ? -2.0f * K2 : -1.0f;
    const float kb  = (t == 2) ? K2 : 1.0f;

    // Runtime probe of row_ror source units -> direction-agnostic W indexing.
    const int j1 = dppi<ROR4>(q);
    const int j2 = dppi<ROR8>(q);
    const int j3 = dppi<ROR12>(q);

    const float4 wrow = reinterpret_cast<const float4*>(W_hh)[row];
    auto wsel = [&](int j) -> float {
        return j == 0 ? wrow.x : j == 1 ? wrow.y : j == 2 ? wrow.z : wrow.w;
    };
    const float Wx0 = s * wsel(q);    // own h (h_q)
    const float Wx1 = s * wsel(j1);   // h arriving via ror4
    const float Wx2 = s * wsel(j2);   // via ror8
    const float Wx3 = s * wsel(j3);   // via ror12
    const float wxi = s * W_ih[row];
    const float yb  = s * (b_ih[row] + b_hh[row]);

    // Store fix (R2 bug was here): slot hp[t0*4 + r] = hs[b][t0+q][t] needs
    // h of unit t at step t0+q. At inner step j==q the lane holds step-j h of
    // ALL units: own h = unit q, hx1 = unit j1, hx2 = unit j2, hx3 = unit j3.
    // sel picks the one whose source unit == t.
    const int sel = (t == q) ? 0 : (t == j1) ? 1 : (t == j2) ? 2 : 3;

    const float* xp = x + (size_t)b * TT;
    float*       hp = hs + (size_t)b * TT * 4;

    float c = 0.0f, h = 0.0f, hx1 = 0.0f, hx2 = 0.0f, hx3 = 0.0f;

    // x prefetch pipeline, distance 2 iterations (8 steps)
    float4 xa = *reinterpret_cast<const float4*>(xp);
    float4 xb = *reinterpret_cast<const float4*>(xp + 4);

    for (int t0 = 0; t0 < TT; t0 += 4) {
        int tpre = t0 + 8;
        tpre = (tpre > TT - 4) ? (TT - 4) : tpre;
        const float4 xn = *reinterpret_cast<const float4*>(xp + tpre);

        float hsave = 0.0f;

        #pragma unroll
        for (int j = 0; j < 4; ++j) {
            const float xt = j == 0 ? xa.x : j == 1 ? xa.y : j == 2 ? xa.z : xa.w;

            // gate pre-activation (already exp2-scaled)
            float y = fmaf(Wx0, h, fmaf(xt, wxi, yb));
            y = fmaf(Wx1, hx1, y);
            y = y + fmaf(Wx3, hx3, Wx2 * hx2);

            // unified activation
            const float rr  = rcpf_(1.0f + ex2(y));
            const float act = fmaf(ka, rr, kb);

            // gather i,f,g,o of this unit (quad_perm broadcasts, unambiguous)
            const float gi = dppf<QB0>(act);
            const float gf = dppf<QB1>(act);
            const float gg = dppf<QB2>(act);   // = K2 * tanh(ag)
            const float go = dppf<QB3>(act);

            // c state in K2-scaled form
            c = fmaf(gf, c, gi * gg);

            // h = o * tanh(c_true), fused: h = go - 2*go*r2
            const float r2 = rcpf_(1.0f + ex2(c));
            h = fmaf(-2.0f * go, r2, go);

            // distribute h_q across quads for next step's dot
            hx1 = dppf<ROR4>(h);
            hx2 = dppf<ROR8>(h);
            hx3 = dppf<ROR12>(h);

            // batched-store save: step t0+q, unit t (see sel above)
            if (j == q) {
                hsave = (sel == 0) ? h : (sel == 1) ? hx1 : (sel == 2) ? hx2 : hx3;
            }
        }

        // 16 lanes -> 64B fully contiguous per sequence, one store per 4 steps
        hp[t0 * 4 + r] = hsave;

        xa = xb;
        xb = xn;
    }
}

// FC epilogue: out[b][t][c] = dot(hs[b][t][:], W_fc[c][:]) + b_fc[c]
// 32-lane groups; lane c in [0,29) computes class c for one (b,t) per iter.
__global__ __launch_bounds__(256) void fc_kernel(
    const float* __restrict__ hs,     // (B*T, 4)
    const float* __restrict__ W_fc,   // (29, 4)
    const float* __restrict__ b_fc,   // (29,)
    float* __restrict__ out)          // (B*T, 29)
{
    const int lane    = threadIdx.x & 31;
    const int group   = (blockIdx.x * blockDim.x + threadIdx.x) >> 5;
    const int ngroups = (gridDim.x * blockDim.x) >> 5;

    const int cc = (lane < NC) ? lane : 0;
    const float4 w   = reinterpret_cast<const float4*>(W_fc)[cc];
    const float bias = b_fc[cc];

    const int NBT = BB * TT;
    for (int bt = group; bt < NBT; bt += ngroups) {
        const float4 h = reinterpret_cast<const float4*>(hs)[bt];
        float v = fmaf(w.x, h.x, fmaf(w.y, h.y, fmaf(w.z, h.z, fmaf(w.w, h.w, bias))));
        if (lane < NC) out[(size_t)bt * NC + lane] = v;
    }
}

extern "C" void kernel_launch(void* const* d_in, const int* in_sizes, int n_in,
                              void* d_out, int out_size, void* d_ws, size_t ws_size,
                              hipStream_t stream) {
    const float* x    = (const float*)d_in[0];
    const float* W_ih = (const float*)d_in[1];
    const float* W_hh = (const float*)d_in[2];
    const float* b_ih = (const float*)d_in[3];
    const float* b_hh = (const float*)d_in[4];
    const float* W_fc = (const float*)d_in[5];
    const float* b_fc = (const float*)d_in[6];
    float* out = (float*)d_out;
    float* hs  = (float*)d_ws;   // needs B*T*4*4 = 16.384 MB

    // Recurrence: 256 seqs x 16 lanes = 4096 threads = 64 single-wave blocks
    lstm_kernel<<<64, 64, 0, stream>>>(x, W_ih, W_hh, b_ih, b_hh, hs);

    // FC: memory-bound epilogue
    fc_kernel<<<4096, 256, 0, stream>>>(hs, W_fc, b_fc, out);
}

// Round 4
// 592.055 us; speedup vs baseline: 1.2580x; 1.1706x over previous
//
#include <hip/hip_runtime.h>

// Problem constants (reference: B=256, T=4000, H=4, 29 classes)
#define HH 4
#define BB 256
#define TT 4000
#define NC 29

// ---- DPP helpers (compile-time ctrl) ----
template<int CTRL>
__device__ __forceinline__ int dppi(int v) {
    return __builtin_amdgcn_mov_dpp(v, CTRL, 0xF, 0xF, true);
}
template<int CTRL>
__device__ __forceinline__ float dppf(float v) {
    return __int_as_float(dppi<CTRL>(__float_as_int(v)));
}
#define QB0   0x00   // quad_perm broadcast lane0 of quad
#define QB1   0x55
#define QB2   0xAA
#define QB3   0xFF
#define ROR4  0x124  // row_ror:4  (within 16-lane row)
#define ROR8  0x128  // row_ror:8
#define ROR12 0x12C  // row_ror:12

__device__ __forceinline__ float ex2(float x) { return __builtin_amdgcn_exp2f(x); }
__device__ __forceinline__ float rcpf_(float x) { return __builtin_amdgcn_rcpf(x); }

// 16 lanes per sequence: lane = q*4 + t, q = unit (0..3), t = gate type
// (0=i,1=f,2=g,3=o). Lane owns W_hh row = t*4+q.
//
// exp2 pre-scaling (verified R3):
//   sigmoid gates: act = 1 - rcp(1 + exp2(a*log2e))
//   g gate:        act = K2*tanh = K2 - 2*K2*rcp(1 + exp2(a*2log2e)), K2=2log2e
//   c kept K2-scaled so tanh(c_true) = 1 - 2*rcp(1 + exp2(c_state)).
//
// R4 restructure (chain 15 -> 14 levels): h never enters the recurrence.
//   h_j = go_j - 2*go_j*r2_j  where r2 = rcp(1+exp2(c)), so
//   y(t+1) = P + sum_j Un_j * r2_j(t),   Un_j = (-2*W_j)*go_j(t)  [off-path]
//   P      = sum_j W_j*go_j(t) + pre(t+1)                         [off-path]
// go/r2 rotations replace the old h rotation; first on-path use of r2 overlaps
// the rors, deleting the h-fma level from the serial chain.
__global__ __launch_bounds__(64, 1) void lstm_kernel(
    const float* __restrict__ x,      // (B, T)
    const float* __restrict__ W_ih,   // (16, 1)
    const float* __restrict__ W_hh,   // (16, 4)
    const float* __restrict__ b_ih,   // (16,)
    const float* __restrict__ b_hh,   // (16,)
    float* __restrict__ hs)           // (B, T, 4) workspace
{
    const int lane = threadIdx.x;        // one wave per block
    const int sl   = lane >> 4;          // sequence slot (0..3)
    const int r    = lane & 15;
    const int q    = r >> 2;             // hidden unit
    const int t    = r & 3;              // gate type
    const int b    = blockIdx.x * 4 + sl;
    const int row  = t * 4 + q;

    const float L2E = 1.4426950408889634f;
    const float K2  = 2.0f * L2E;
    const float s   = (t == 2) ? K2 : L2E;
    const float ka  = (t == 2) ? -2.0f * K2 : -1.0f;
    const float kb  = (t == 2) ? K2 : 1.0f;

    // Runtime probe of row_ror source units -> direction-agnostic W indexing.
    const int j1 = dppi<ROR4>(q);
    const int j2 = dppi<ROR8>(q);
    const int j3 = dppi<ROR12>(q);

    const float4 wrow = reinterpret_cast<const float4*>(W_hh)[row];
    auto wsel = [&](int j) -> float {
        return j == 0 ? wrow.x : j == 1 ? wrow.y : j == 2 ? wrow.z : wrow.w;
    };
    const float Wx0 = s * wsel(q);    // pairs with own go/r2
    const float Wx1 = s * wsel(j1);   // pairs with ror4-arrived values
    const float Wx2 = s * wsel(j2);
    const float Wx3 = s * wsel(j3);
    const float n2W0 = -2.0f * Wx0;
    const float n2W1 = -2.0f * Wx1;
    const float n2W2 = -2.0f * Wx2;
    const float n2W3 = -2.0f * Wx3;
    const float wxi = s * W_ih[row];
    const float yb  = s * (b_ih[row] + b_hh[row]);

    // Store select (verified R3): slot hp[t0*4 + r] = hs[b][t0+q][t] wants
    // h of unit t at step t0+q; at inner step j==q the lane can form h of
    // all units from {own,(ror4),(ror8),(ror12)} go/r2 pairs; sel picks
    // the one whose source unit == t.
    const int sel = (t == q) ? 0 : (t == j1) ? 1 : (t == j2) ? 2 : 3;

    const float* xp = x + (size_t)b * TT;
    float*       hp = hs + (size_t)b * TT * 4;

    float c = 0.0f;
    float r2 = 0.0f, r2x1 = 0.0f, r2x2 = 0.0f, r2x3 = 0.0f;
    float U0 = 0.0f, U1 = 0.0f, U2 = 0.0f, U3 = 0.0f;

    // x prefetch pipeline, distance 2 iterations (8 steps)
    float4 xa = *reinterpret_cast<const float4*>(xp);
    float4 xb = *reinterpret_cast<const float4*>(xp + 4);

    float P = fmaf(xa.x, wxi, yb);   // y(0) = pre(0) since U's are 0

    for (int t0 = 0; t0 < TT; t0 += 4) {
        int tpre = t0 + 8;
        tpre = (tpre > TT - 4) ? (TT - 4) : tpre;
        const float4 xn = *reinterpret_cast<const float4*>(xp + tpre);

        float hsave = 0.0f;

        #pragma unroll
        for (int j = 0; j < 4; ++j) {
            // x of the NEXT step (j==3 -> first element of next chunk)
            const float xnx = j == 0 ? xa.y : j == 1 ? xa.z : j == 2 ? xa.w : xb.x;

            // --- on-path: y from previous step's (go, r2) expansion ---
            float y = fmaf(U1, r2x1, fmaf(U0, r2, P));
            y = y + fmaf(U3, r2x3, U2 * r2x2);

            const float rr  = rcpf_(1.0f + ex2(y));
            const float act = fmaf(ka, rr, kb);

            // gather i,f,g,o of this unit (quad_perm)
            const float gi = dppf<QB0>(act);
            const float gf = dppf<QB1>(act);
            const float gg = dppf<QB2>(act);   // = K2 * tanh(ag)
            const float go = dppf<QB3>(act);

            c = fmaf(gf, c, gi * gg);

            // --- off-path while exp2(c) cooks: next step's P and U's ---
            const float gox1 = dppf<ROR4>(go);
            const float gox2 = dppf<ROR8>(go);
            const float gox3 = dppf<ROR12>(go);
            const float pre  = fmaf(xnx, wxi, yb);
            float Pn = fmaf(Wx1, gox1, fmaf(Wx0, go, pre));
            Pn = Pn + fmaf(Wx3, gox3, Wx2 * gox2);
            const float U0n = n2W0 * go;
            const float U1n = n2W1 * gox1;
            const float U2n = n2W2 * gox2;
            const float U3n = n2W3 * gox3;

            // --- on-path: cell nonlinearity ---
            const float r2n = rcpf_(1.0f + ex2(c));
            const float r2n1 = dppf<ROR4>(r2n);
            const float r2n2 = dppf<ROR8>(r2n);
            const float r2n3 = dppf<ROR12>(r2n);

            // store machinery (off-path): reconstruct h of the needed unit
            if (j == q) {
                const float gsel = (sel == 0) ? go  : (sel == 1) ? gox1
                                 : (sel == 2) ? gox2 : gox3;
                const float rsel = (sel == 0) ? r2n : (sel == 1) ? r2n1
                                 : (sel == 2) ? r2n2 : r2n3;
                hsave = fmaf(-2.0f * gsel, rsel, gsel);
            }

            // commit next-step state
            r2 = r2n; r2x1 = r2n1; r2x2 = r2n2; r2x3 = r2n3;
            U0 = U0n; U1 = U1n; U2 = U2n; U3 = U3n;
            P  = Pn;
        }

        // 16 lanes -> 64B contiguous per sequence, one store per 4 steps
        hp[t0 * 4 + r] = hsave;

        xa = xb;
        xb = xn;
    }
}

// FC epilogue, full-line aligned writes:
// 16 output rows = 464 floats = 1856 B = exactly 29 x 64B lines.
// Each block-iteration covers 232 consecutive float4 (threads 0..231), so
// every 64B line is written whole -> no write-allocate RMW.
__global__ __launch_bounds__(256) void fc_kernel(
    const float* __restrict__ hs,     // (B*T, 4)
    const float* __restrict__ W_fc,   // (29, 4)
    const float* __restrict__ b_fc,   // (29,)
    float* __restrict__ out)          // (B*T, 29)
{
    const int total_f4 = BB * TT * NC / 4;   // 7,424,000
    const int tid = threadIdx.x;

    for (int base = blockIdx.x * 232; base < total_f4; base += gridDim.x * 232) {
        if (tid < 232) {
            const int f4 = base + tid;
            const unsigned e0 = (unsigned)f4 * 4u;
            float v[4];
            #pragma unroll
            for (int k = 0; k < 4; ++k) {
                const unsigned e   = e0 + k;
                const unsigned row = e / 29u;            // magic-mul
                const unsigned cls = e - row * 29u;
                const float4 h = reinterpret_cast<const float4*>(hs)[row];
                const float4 w = reinterpret_cast<const float4*>(W_fc)[cls];
                v[k] = fmaf(w.x, h.x, fmaf(w.y, h.y,
                        fmaf(w.z, h.z, fmaf(w.w, h.w, b_fc[cls]))));
            }
            reinterpret_cast<float4*>(out)[f4] = make_float4(v[0], v[1], v[2], v[3]);
        }
    }
}

extern "C" void kernel_launch(void* const* d_in, const int* in_sizes, int n_in,
                              void* d_out, int out_size, void* d_ws, size_t ws_size,
                              hipStream_t stream) {
    const float* x    = (const float*)d_in[0];
    const float* W_ih = (const float*)d_in[1];
    const float* W_hh = (const float*)d_in[2];
    const float* b_ih = (const float*)d_in[3];
    const float* b_hh = (const float*)d_in[4];
    const float* W_fc = (const float*)d_in[5];
    const float* b_fc = (const float*)d_in[6];
    float* out = (float*)d_out;
    float* hs  = (float*)d_ws;   // needs B*T*4*4 = 16.384 MB

    // Recurrence: 256 seqs x 16 lanes = 64 single-wave blocks
    lstm_kernel<<<64, 64, 0, stream>>>(x, W_ih, W_hh, b_ih, b_hh, hs);

    // FC: memory-bound epilogue (32,000 block-iterations total)
    fc_kernel<<<4096, 256, 0, stream>>>(hs, W_fc, b_fc, out);
}